// Round 3
// baseline (292.050 us; speedup 1.0000x reference)
//
#include <hip/hip_runtime.h>
#include <math.h>

// out = sum_j W[j] * (sum_n |yt[n,j]-yp[n,j]|) / (sum_n yt[n,j])
// (outer mean's 1/N cancels the 1/N inside col_mean)
//
// R10 = fused single-kernel (last-block finalize). BW axis is closed:
// R8/R9 nt-load kernel is < 49 us (invisible below the 49-us harness fills)
// => >= 3.43 TB/s read, which triangulates with (a) m13 copy read-half
// ~3.15 TB/s, (b) MSHR model 32 lines/CU x 128B / ~300ns L3-hit ~ 3.5 TB/s.
// Seven access mechanisms never beat it -> CU-issued read-stream ceiling.
// Remaining controllable time = finalize launch (~5-8 us 1-block latency).
// Fuse via ticket counter: hipMemsetAsync zeroes counter each replay (legal
// capturable node), blocks store partials + release-fence + atomicAdd; last
// block acquire-fences (cross-XCD L2 non-coherence, Guideline 16) and
// reduces 2048x10 partials in a FIXED order (deterministic).
//
// Column math (R2): float4 q = tid + k*TTH, component c -> col (4q+c)%5;
// 4*TTH mod 5 == 2 -> col = (c + 2k + 4*tid)%5. (c+2k)%5 static after
// unroll; per-thread rotation un-done once at the end.

#define GRID 2048
#define BLOCK 256
#define TTH (GRID * BLOCK)  // 524288; 4*TTH mod 5 == 2
#define KLOADS 10           // 524288*10 = 5242880 float4s per array, exact

typedef float vf4 __attribute__((ext_vector_type(4)));

__global__ __launch_bounds__(BLOCK, 8) void regress_fused(
    const vf4* __restrict__ yt4, const vf4* __restrict__ yp4,
    float* __restrict__ partials, unsigned int* __restrict__ counter,
    float* __restrict__ out) {
  const int tid = blockIdx.x * BLOCK + threadIdx.x;

  // rotated-space accumulators: local m corresponds to column (m + 4*tid)%5
  float s[5] = {0.f, 0.f, 0.f, 0.f, 0.f};
  float a[5] = {0.f, 0.f, 0.f, 0.f, 0.f};

#pragma unroll
  for (int k = 0; k < KLOADS; ++k) {
    const vf4 tv = __builtin_nontemporal_load(yt4 + tid + (long long)k * TTH);
    const vf4 pv = __builtin_nontemporal_load(yp4 + tid + (long long)k * TTH);
    const int m0 = (2 * k + 0) % 5;  // static after unroll
    const int m1 = (2 * k + 1) % 5;
    const int m2 = (2 * k + 2) % 5;
    const int m3 = (2 * k + 3) % 5;
    s[m0] += tv.x; a[m0] += fabsf(tv.x - pv.x);
    s[m1] += tv.y; a[m1] += fabsf(tv.y - pv.y);
    s[m2] += tv.z; a[m2] += fabsf(tv.z - pv.z);
    s[m3] += tv.w; a[m3] += fabsf(tv.w - pv.w);
  }

  // un-rotate into global column space + block reduction via LDS
  __shared__ float red[BLOCK][11];  // +1 pad; red[0][10] doubles as last-flag
  const int tix = threadIdx.x;
  const int rr = tid % 5;
#pragma unroll
  for (int m = 0; m < 5; ++m) {
    int g = m - rr; if (g < 0) g += 5;
    red[tix][g] = s[m];
    red[tix][5 + g] = a[m];
  }
  __syncthreads();
#pragma unroll
  for (int off = BLOCK / 2; off > 0; off >>= 1) {
    if (tix < off) {
#pragma unroll
      for (int v = 0; v < 10; ++v) red[tix][v] += red[tix + off][v];
    }
    __syncthreads();
  }
  if (tix < 10) partials[blockIdx.x * 10 + tix] = red[0][tix];  // wave-0 stores

  // ticket: thread 0 is in the same wave as the partials stores, so its
  // release fence orders them device-wide before the atomic.
  if (tix == 0) {
    __threadfence();  // release: write back partials past this XCD's L2
    unsigned int tk = atomicAdd(counter, 1u);
    red[0][10] = (tk == GRID - 1) ? 1.0f : 0.0f;
  }
  __syncthreads();
  if (red[0][10] == 0.0f) return;

  // ---- last block: finalize ----
  __threadfence();  // acquire: invalidate potentially-stale cached partials

  // deterministic reduce of partials[2048][10]:
  // 250 threads; thread t owns column v=t%10, chunk c=t/10 (25 chunks of 82)
  __shared__ float red2[26][10];
  float acc = 0.f;
  if (tix < 250) {
    const int v = tix % 10;
    const int c = tix / 10;
    const int r0 = c * 82;
    const int r1 = (r0 + 82 < GRID) ? (r0 + 82) : GRID;
    for (int r = r0; r < r1; ++r) acc += partials[r * 10 + v];  // fixed order
    red2[c][v] = acc;
  }
  __syncthreads();
  if (tix < 10) {
    float s2 = 0.f;
#pragma unroll
    for (int c = 0; c < 25; ++c) s2 += red2[c][tix];  // fixed order
    red2[25][tix] = s2;
  }
  __syncthreads();
  if (tix == 0) {
    const float W[5] = {0.3f, 0.175f, 0.175f, 0.175f, 0.175f};
    float r = 0.f;
#pragma unroll
    for (int c = 0; c < 5; ++c) r += W[c] * red2[25][5 + c] / red2[25][c];
    *out = r;
  }
}

// generic fallback (any nrows), correctness-first
__global__ __launch_bounds__(BLOCK) void regress_reduce_generic(
    const float* __restrict__ yt, const float* __restrict__ yp,
    float* __restrict__ partials, long long nrows) {
  float s[5] = {0.f, 0.f, 0.f, 0.f, 0.f};
  float a[5] = {0.f, 0.f, 0.f, 0.f, 0.f};
  const long long tid = (long long)blockIdx.x * blockDim.x + threadIdx.x;
  const long long stride = (long long)gridDim.x * blockDim.x;
  for (long long r = tid; r < nrows; r += stride) {
#pragma unroll
    for (int c = 0; c < 5; ++c) {
      float tv = yt[r * 5 + c];
      s[c] += tv;
      a[c] += fabsf(tv - yp[r * 5 + c]);
    }
  }
  __shared__ float red[BLOCK][11];
  const int t = threadIdx.x;
#pragma unroll
  for (int c = 0; c < 5; ++c) { red[t][c] = s[c]; red[t][5 + c] = a[c]; }
  __syncthreads();
#pragma unroll
  for (int off = BLOCK / 2; off > 0; off >>= 1) {
    if (t < off) {
#pragma unroll
      for (int v = 0; v < 10; ++v) red[t][v] += red[t + off][v];
    }
    __syncthreads();
  }
  if (t < 10) partials[blockIdx.x * 10 + t] = red[0][t];
}

__global__ __launch_bounds__(256) void regress_finalize(
    const float* __restrict__ partials, int nblocks, float* __restrict__ out) {
  float acc[10] = {0.f, 0.f, 0.f, 0.f, 0.f, 0.f, 0.f, 0.f, 0.f, 0.f};
  for (int b = threadIdx.x; b < nblocks; b += 256) {
#pragma unroll
    for (int v = 0; v < 10; ++v) acc[v] += partials[b * 10 + v];
  }
#pragma unroll
  for (int off = 32; off > 0; off >>= 1) {
#pragma unroll
    for (int v = 0; v < 10; ++v) acc[v] += __shfl_down(acc[v], off, 64);
  }
  __shared__ float lds[4][10];
  const int lane = threadIdx.x & 63;
  const int wave = threadIdx.x >> 6;
  if (lane == 0) {
#pragma unroll
    for (int v = 0; v < 10; ++v) lds[wave][v] = acc[v];
  }
  __syncthreads();
  if (threadIdx.x == 0) {
    const float W[5] = {0.3f, 0.175f, 0.175f, 0.175f, 0.175f};
    float r = 0.f;
#pragma unroll
    for (int c = 0; c < 5; ++c) {
      float sc = lds[0][c] + lds[1][c] + lds[2][c] + lds[3][c];
      float ac = lds[0][5 + c] + lds[1][5 + c] + lds[2][5 + c] + lds[3][5 + c];
      r += W[c] * ac / sc;
    }
    *out = r;
  }
}

extern "C" void kernel_launch(void* const* d_in, const int* in_sizes, int n_in,
                              void* d_out, int out_size, void* d_ws, size_t ws_size,
                              hipStream_t stream) {
  const float* yt = (const float*)d_in[0];
  const float* yp = (const float*)d_in[1];
  const long long nelem = (long long)in_sizes[0];
  const long long nrows = nelem / 5;
  float* partials = (float*)d_ws;                     // GRID*10 floats = 80 KB
  unsigned int* counter =
      (unsigned int*)((char*)d_ws + GRID * 10 * sizeof(float));  // +4 B

  if (nelem == (long long)TTH * KLOADS * 4) {
    hipMemsetAsync(counter, 0, sizeof(unsigned int), stream);  // capturable
    regress_fused<<<GRID, BLOCK, 0, stream>>>(
        (const vf4*)yt, (const vf4*)yp, partials, counter, (float*)d_out);
  } else {
    regress_reduce_generic<<<GRID, BLOCK, 0, stream>>>(yt, yp, partials, nrows);
    regress_finalize<<<1, 256, 0, stream>>>(partials, GRID, (float*)d_out);
  }
}